// Round 1
// baseline (15467.262 us; speedup 1.0000x reference)
//
#include <hip/hip_runtime.h>

// LSTM forward, B=32 T=1024 D=512 U=512, fp32.
// Persistent fused kernel: 8 groups x 4 batches; 32 WGs/group; each WG owns
// 16 units (64 gate-columns) with R+K weight slices held in VGPRs.
// x-projection for step t+1 computed before the spin on h_t (hides in sync).
// d_out doubles as the h history buffer. ws holds per-(group,step) flags only.

#define TT 1024
#define DD 512
#define UU 512
#define NCOL 2048

__global__ void zero_flags_kernel(int* f, int n) {
  int i = blockIdx.x * blockDim.x + threadIdx.x;
  if (i < n) f[i] = 0;
}

__device__ __forceinline__ float hsig(float v) {
  return fminf(fmaxf(0.2f * v + 0.5f, 0.0f), 1.0f);
}

// 64-long dot for 4 batch streams against a 64-entry register weight slice.
__device__ __forceinline__ void dot64_4(const float* p0, const float* p1,
                                        const float* p2, const float* p3,
                                        const float (&W)[64],
                                        float& a0, float& a1, float& a2, float& a3) {
  a0 = 0.f; a1 = 0.f; a2 = 0.f; a3 = 0.f;
#pragma unroll
  for (int j4 = 0; j4 < 16; ++j4) {
    float4 v0 = *(const float4*)(p0 + j4 * 4);
    float4 v1 = *(const float4*)(p1 + j4 * 4);
    float4 v2 = *(const float4*)(p2 + j4 * 4);
    float4 v3 = *(const float4*)(p3 + j4 * 4);
    float w0 = W[4 * j4 + 0], w1 = W[4 * j4 + 1];
    float w2 = W[4 * j4 + 2], w3 = W[4 * j4 + 3];
    a0 += v0.x * w0 + v0.y * w1 + v0.z * w2 + v0.w * w3;
    a1 += v1.x * w0 + v1.y * w1 + v1.z * w2 + v1.w * w3;
    a2 += v2.x * w0 + v2.y * w1 + v2.z * w2 + v2.w * w3;
    a3 += v3.x * w0 + v3.y * w1 + v3.z * w2 + v3.w * w3;
  }
}

__global__ __launch_bounds__(512, 2) void lstm_persistent(
    const float* __restrict__ x,
    const float* __restrict__ Wk,
    const float* __restrict__ Wr,
    const float* __restrict__ bias,
    float* __restrict__ out,
    int* __restrict__ flags) {
  const int tid = (int)threadIdx.x;
  const int c   = tid & 63;   // local column 0..63 (gate*16 + u16)
  const int q   = tid >> 6;   // k-octant 0..7 (rows q*64..q*64+63)
  const int g   = (int)blockIdx.x & 7;   // group (intended XCD)
  const int w   = (int)blockIdx.x >> 3;  // unit block 0..31
  const int gate = c >> 4;
  const int u16  = c & 15;
  const int gcol = gate * UU + w * 16 + u16;  // global column in [0,2048)

  // Weight slices resident in VGPRs for the whole kernel.
  float Kreg[64], Rreg[64];
#pragma unroll
  for (int j = 0; j < 64; ++j) Kreg[j] = Wk[(size_t)(q * 64 + j) * NCOL + gcol];
#pragma unroll
  for (int j = 0; j < 64; ++j) Rreg[j] = Wr[(size_t)(q * 64 + j) * NCOL + gcol];

  __shared__ float LX[8][4][64];   // x-projection partials (per octant)
  __shared__ float LR[8][4][64];   // recurrent partials
  __shared__ float LXZ[2][4][64];  // reduced xz, parity-buffered by t
  __shared__ float LB[64];         // bias slice

  if (tid < 64) LB[tid] = bias[(tid >> 4) * UU + w * 16 + (tid & 15)];

  const int b_own = tid >> 4;  // used by tid<64 update threads
  const int u_own = tid & 15;
  float c_state = 0.0f;

  int* gflags = flags + g * TT;

  const float* xb0 = x + (size_t)(g * 4 + 0) * TT * DD + q * 64;
  const float* xb1 = x + (size_t)(g * 4 + 1) * TT * DD + q * 64;
  const float* xb2 = x + (size_t)(g * 4 + 2) * TT * DD + q * 64;
  const float* xb3 = x + (size_t)(g * 4 + 3) * TT * DD + q * 64;
  const float* hb0 = out + (size_t)(g * 4 + 0) * TT * UU + q * 64;
  const float* hb1 = out + (size_t)(g * 4 + 1) * TT * UU + q * 64;
  const float* hb2 = out + (size_t)(g * 4 + 2) * TT * UU + q * 64;
  const float* hb3 = out + (size_t)(g * 4 + 3) * TT * UU + q * 64;

  // ---- prologue: xz for t=0 ----
  {
    float a0, a1, a2, a3;
    dot64_4(xb0, xb1, xb2, xb3, Kreg, a0, a1, a2, a3);
    LX[q][0][c] = a0; LX[q][1][c] = a1; LX[q][2][c] = a2; LX[q][3][c] = a3;
  }
  __syncthreads();
  if (tid < 256) {
    int b2 = tid >> 6, c2 = tid & 63;
    float s = 0.f;
#pragma unroll
    for (int qq = 0; qq < 8; ++qq) s += LX[qq][b2][c2];
    LXZ[0][b2][c2] = s;
  }
  __syncthreads();

  for (int t = 0; t < TT; ++t) {
    // ---- Phase A: x-projection for step t+1 (independent of h_t) ----
    if (t + 1 < TT) {
      float a0, a1, a2, a3;
      size_t off = (size_t)(t + 1) * DD;
      dot64_4(xb0 + off, xb1 + off, xb2 + off, xb3 + off, Kreg, a0, a1, a2, a3);
      LX[q][0][c] = a0; LX[q][1][c] = a1; LX[q][2][c] = a2; LX[q][3][c] = a3;
    }
    // ---- wait for h_{t-1} from all 32 WGs of this group ----
    if (t > 0 && tid == 0) {
      while (__hip_atomic_load(gflags + (t - 1), __ATOMIC_ACQUIRE,
                               __HIP_MEMORY_SCOPE_AGENT) < 32) {
        __builtin_amdgcn_s_sleep(1);
      }
    }
    __syncthreads();
    // ---- Phase B: recurrent projection h_{t-1} @ R ----
    if (t > 0) {
      float r0, r1, r2, r3;
      size_t off = (size_t)(t - 1) * UU;
      dot64_4(hb0 + off, hb1 + off, hb2 + off, hb3 + off, Rreg, r0, r1, r2, r3);
      LR[q][0][c] = r0; LR[q][1][c] = r1; LR[q][2][c] = r2; LR[q][3][c] = r3;
    }
    __syncthreads();
    // ---- Phase C: reduce xz_{t+1} into parity slot ----
    if (t + 1 < TT && tid < 256) {
      int b2 = tid >> 6, c2 = tid & 63;
      float s = 0.f;
#pragma unroll
      for (int qq = 0; qq < 8; ++qq) s += LX[qq][b2][c2];
      LXZ[(t + 1) & 1][b2][c2] = s;
    }
    // ---- Phase C2: gates, state update, h store ----
    if (tid < 64) {
      float s0 = LXZ[t & 1][b_own][u_own +  0] + LB[u_own +  0];
      float s1 = LXZ[t & 1][b_own][u_own + 16] + LB[u_own + 16];
      float s2 = LXZ[t & 1][b_own][u_own + 32] + LB[u_own + 32];
      float s3 = LXZ[t & 1][b_own][u_own + 48] + LB[u_own + 48];
      if (t > 0) {
#pragma unroll
        for (int qq = 0; qq < 8; ++qq) {
          s0 += LR[qq][b_own][u_own +  0];
          s1 += LR[qq][b_own][u_own + 16];
          s2 += LR[qq][b_own][u_own + 32];
          s3 += LR[qq][b_own][u_own + 48];
        }
      }
      float gi = hsig(s0);
      float gf = hsig(s1);
      float gc = tanhf(s2);
      float go = hsig(s3);
      c_state = gf * c_state + gi * gc;
      float h = go * tanhf(c_state);
      out[((size_t)(g * 4 + b_own) * TT + t) * UU + w * 16 + u_own] = h;
      __threadfence();  // wave0-uniform: agent-scope release of h stores
    }
    __syncthreads();
    if (tid == 0) {
      __hip_atomic_fetch_add(gflags + t, 1, __ATOMIC_RELEASE,
                             __HIP_MEMORY_SCOPE_AGENT);
    }
  }
}

extern "C" void kernel_launch(void* const* d_in, const int* in_sizes, int n_in,
                              void* d_out, int out_size, void* d_ws, size_t ws_size,
                              hipStream_t stream) {
  const float* x    = (const float*)d_in[0];
  const float* Wk   = (const float*)d_in[1];
  const float* Wr   = (const float*)d_in[2];
  const float* bias = (const float*)d_in[3];
  float* out = (float*)d_out;
  int* flags = (int*)d_ws;  // 8 groups x 1024 steps = 32KB

  zero_flags_kernel<<<32, 256, 0, stream>>>(flags, 8 * TT);
  lstm_persistent<<<256, 512, 0, stream>>>(x, Wk, Wr, bias, out, flags);
}

// Round 2
// 7013.580 us; speedup vs baseline: 2.2053x; 2.2053x over previous
//
#include <hip/hip_runtime.h>

// LSTM forward, B=32 T=1024 D=512 U=512, fp32.
// Persistent fused kernel: 8 groups x 4 batches; 32 WGs/group; each WG owns
// 16 units (64 gate-columns) with R+K weight slices held in registers.
// Sync redesign vs R1: NO ordered atomics / threadfence (those emit
// buffer_inv / wbl2 on gfx950 multi-XCD and cost ~14us/step). Instead:
// per-access coherent (RELAXED+AGENT) loads/stores for h and flags, producer
// orders h-store -> flag-add with s_waitcnt vmcnt(0). h[t-1] staged to LDS
// once per WG; dot reads are wave-uniform ds_read_b128 broadcasts.

#define TT 1024
#define DD 512
#define UU 512
#define NCOL 2048

__global__ void zero_flags_kernel(int* f, int n) {
  int i = blockIdx.x * blockDim.x + threadIdx.x;
  if (i < n) f[i] = 0;
}

__device__ __forceinline__ float hsig(float v) {
  return fminf(fmaxf(0.2f * v + 0.5f, 0.0f), 1.0f);
}

__device__ __forceinline__ float tanh_fast(float x) {
  // |err| ~1e-6 abs; exp overflow/underflow saturate correctly to +/-1.
  float e = __expf(2.0f * x);
  return 1.0f - 2.0f / (e + 1.0f);
}

// 64-long dot for 4 streams against a 64-entry register weight slice.
// Pointers may be global (x) or LDS (h staged); float4 reads, 16B aligned.
__device__ __forceinline__ void dot64_4(const float* p0, const float* p1,
                                        const float* p2, const float* p3,
                                        const float (&W)[64],
                                        float& a0, float& a1, float& a2, float& a3) {
  a0 = 0.f; a1 = 0.f; a2 = 0.f; a3 = 0.f;
#pragma unroll
  for (int j4 = 0; j4 < 16; ++j4) {
    float4 v0 = *(const float4*)(p0 + j4 * 4);
    float4 v1 = *(const float4*)(p1 + j4 * 4);
    float4 v2 = *(const float4*)(p2 + j4 * 4);
    float4 v3 = *(const float4*)(p3 + j4 * 4);
    float w0 = W[4 * j4 + 0], w1 = W[4 * j4 + 1];
    float w2 = W[4 * j4 + 2], w3 = W[4 * j4 + 3];
    a0 += v0.x * w0 + v0.y * w1 + v0.z * w2 + v0.w * w3;
    a1 += v1.x * w0 + v1.y * w1 + v1.z * w2 + v1.w * w3;
    a2 += v2.x * w0 + v2.y * w1 + v2.z * w2 + v2.w * w3;
    a3 += v3.x * w0 + v3.y * w1 + v3.z * w2 + v3.w * w3;
  }
}

__global__ __launch_bounds__(512, 2) void lstm_persistent(
    const float* __restrict__ x,
    const float* __restrict__ Wk,
    const float* __restrict__ Wr,
    const float* __restrict__ bias,
    float* __restrict__ out,
    int* __restrict__ flags) {
  const int tid = (int)threadIdx.x;
  const int c   = tid & 63;   // local column 0..63 (gate*16 + u16)
  const int q   = tid >> 6;   // k-octant 0..7 (rows q*64..q*64+63)
  const int g   = (int)blockIdx.x & 7;   // group
  const int w   = (int)blockIdx.x >> 3;  // unit block 0..31
  const int gate = c >> 4;
  const int u16  = c & 15;
  const int gcol = gate * UU + w * 16 + u16;  // global column in [0,2048)

  // Weight slices resident in registers for the whole kernel.
  float Kreg[64], Rreg[64];
#pragma unroll
  for (int j = 0; j < 64; ++j) Kreg[j] = Wk[(size_t)(q * 64 + j) * NCOL + gcol];
#pragma unroll
  for (int j = 0; j < 64; ++j) Rreg[j] = Wr[(size_t)(q * 64 + j) * NCOL + gcol];

  __shared__ float LX[8][4][65];   // x-projection partials (padded: no 4-way conflict)
  __shared__ float LR[8][4][65];   // recurrent partials
  __shared__ float LXZ[2][4][65];  // reduced xz, parity-buffered by t
  __shared__ float LH[4][512];     // h[t-1] staged (broadcast-read, unpadded)
  __shared__ float LB[64];         // bias slice

  if (tid < 64) LB[tid] = bias[(tid >> 4) * UU + w * 16 + (tid & 15)];

  const int b_own = tid >> 4;  // used by tid<64 update threads
  const int u_own = tid & 15;
  float c_state = 0.0f;

  int* gflags = flags + g * TT;

  const float* xb0 = x + (size_t)(g * 4 + 0) * TT * DD + q * 64;
  const float* xb1 = x + (size_t)(g * 4 + 1) * TT * DD + q * 64;
  const float* xb2 = x + (size_t)(g * 4 + 2) * TT * DD + q * 64;
  const float* xb3 = x + (size_t)(g * 4 + 3) * TT * DD + q * 64;

  // ---- prologue: xz for t=0 ----
  {
    float a0, a1, a2, a3;
    dot64_4(xb0, xb1, xb2, xb3, Kreg, a0, a1, a2, a3);
    LX[q][0][c] = a0; LX[q][1][c] = a1; LX[q][2][c] = a2; LX[q][3][c] = a3;
  }
  __syncthreads();
  if (tid < 256) {
    int b2 = tid >> 6, c2 = tid & 63;
    float s = 0.f;
#pragma unroll
    for (int qq = 0; qq < 8; ++qq) s += LX[qq][b2][c2];
    LXZ[0][b2][c2] = s;
  }
  __syncthreads();

  for (int t = 0; t < TT; ++t) {
    // ---- Phase A: x-projection for step t+1 (independent of h_t) ----
    if (t + 1 < TT) {
      float a0, a1, a2, a3;
      size_t off = (size_t)(t + 1) * DD;
      dot64_4(xb0 + off, xb1 + off, xb2 + off, xb3 + off, Kreg, a0, a1, a2, a3);
      LX[q][0][c] = a0; LX[q][1][c] = a1; LX[q][2][c] = a2; LX[q][3][c] = a3;
    }
    // ---- wait for h_{t-1}; then stage it into LDS (coherent loads) ----
    if (t > 0) {
      // All threads poll: per-wave the load coalesces to one LLC request.
      while (__hip_atomic_load(gflags + (t - 1), __ATOMIC_RELAXED,
                               __HIP_MEMORY_SCOPE_AGENT) < 32) {
        __builtin_amdgcn_s_sleep(1);
      }
      asm volatile("" ::: "memory");  // keep staging loads below the poll
#pragma unroll
      for (int k = 0; k < 4; ++k) {
        LH[k][tid] = __hip_atomic_load(
            out + ((size_t)(g * 4 + k) * TT + (t - 1)) * UU + tid,
            __ATOMIC_RELAXED, __HIP_MEMORY_SCOPE_AGENT);
      }
    }
    __syncthreads();
    // ---- Phase B: recurrent projection h_{t-1} @ R (LDS broadcast reads) ----
    if (t > 0) {
      float r0, r1, r2, r3;
      dot64_4(&LH[0][q * 64], &LH[1][q * 64], &LH[2][q * 64], &LH[3][q * 64],
              Rreg, r0, r1, r2, r3);
      LR[q][0][c] = r0; LR[q][1][c] = r1; LR[q][2][c] = r2; LR[q][3][c] = r3;
    }
    __syncthreads();
    // ---- Phase C: reduce xz_{t+1} into parity slot ----
    if (t + 1 < TT && tid < 256) {
      int b2 = tid >> 6, c2 = tid & 63;
      float s = 0.f;
#pragma unroll
      for (int qq = 0; qq < 8; ++qq) s += LX[qq][b2][c2];
      LXZ[(t + 1) & 1][b2][c2] = s;
    }
    // ---- Phase C2: gates, state update, h store (wave 0) ----
    if (tid < 64) {
      float s0 = LXZ[t & 1][b_own][u_own +  0] + LB[u_own +  0];
      float s1 = LXZ[t & 1][b_own][u_own + 16] + LB[u_own + 16];
      float s2 = LXZ[t & 1][b_own][u_own + 32] + LB[u_own + 32];
      float s3 = LXZ[t & 1][b_own][u_own + 48] + LB[u_own + 48];
      if (t > 0) {
#pragma unroll
        for (int qq = 0; qq < 8; ++qq) {
          s0 += LR[qq][b_own][u_own +  0];
          s1 += LR[qq][b_own][u_own + 16];
          s2 += LR[qq][b_own][u_own + 32];
          s3 += LR[qq][b_own][u_own + 48];
        }
      }
      float gi = hsig(s0);
      float gf = hsig(s1);
      float gc = tanh_fast(s2);
      float go = hsig(s3);
      c_state = gf * c_state + gi * gc;
      float h = go * tanh_fast(c_state);
      __hip_atomic_store(
          out + ((size_t)(g * 4 + b_own) * TT + t) * UU + w * 16 + u_own, h,
          __ATOMIC_RELAXED, __HIP_MEMORY_SCOPE_AGENT);
    }
    if (tid == 0) {
      // Ensure wave 0's h stores are at the coherent point, then signal.
      asm volatile("s_waitcnt vmcnt(0)" ::: "memory");
      __hip_atomic_fetch_add(gflags + t, 1, __ATOMIC_RELAXED,
                             __HIP_MEMORY_SCOPE_AGENT);
    }
    __syncthreads();
  }
}

extern "C" void kernel_launch(void* const* d_in, const int* in_sizes, int n_in,
                              void* d_out, int out_size, void* d_ws, size_t ws_size,
                              hipStream_t stream) {
  const float* x    = (const float*)d_in[0];
  const float* Wk   = (const float*)d_in[1];
  const float* Wr   = (const float*)d_in[2];
  const float* bias = (const float*)d_in[3];
  float* out = (float*)d_out;
  int* flags = (int*)d_ws;  // 8 groups x 1024 steps = 32KB

  zero_flags_kernel<<<32, 256, 0, stream>>>(flags, 8 * TT);
  lstm_persistent<<<256, 512, 0, stream>>>(x, Wk, Wr, bias, out, flags);
}

// Round 4
// 6645.222 us; speedup vs baseline: 2.3276x; 1.0554x over previous
//
#include <hip/hip_runtime.h>

// LSTM forward, B=32 T=1024 D=512 U=512, fp32.
// Persistent fused kernel, 256 WGs x 512 thr (all co-resident).
// Group g = blockIdx&7 handles batches 4g..4g+3; WG w = blockIdx>>3 owns
// 16 units (64 gate columns). Weights held in VGPRs (one matrix per thread:
// waves 0-3 hold R-slices, waves 4-7 hold K-slices).
//
// R4 sync: DATAFLOW. d_out (the h history) is memset to 0xFFFFFFFF (-NaN)
// each launch; producers store h via RELAXED+AGENT (LLC) atomic stores;
// consumers poll the h words of step t-1 directly until != 0xFFFFFFFF.
// The polled words ARE the data -> no flags, no fences, no re-load.
// Real h = o*tanh(c), |h|<1, never NaN -> sentinel is unreachable.
//
// Wave specialization per step:
//   waves 0-3: poll h(t-1) -> LDS -> h@R partials -> (wave0) gates+store h(t)
//   waves 4-7: x@K for step t+1 -> reduce into parity LXZ buffer
// so the x-projection GEMM is fully off the critical path.

#define TT 1024
#define DD 512
#define UU 512
#define NCOL 2048
#define SENT 0xFFFFFFFFu

__device__ __forceinline__ float hsig(float v) {
  return fminf(fmaxf(0.2f * v + 0.5f, 0.0f), 1.0f);
}
__device__ __forceinline__ float tanh_fast(float x) {
  float e = __expf(2.0f * x);
  return 1.0f - 2.0f / (e + 1.0f);
}

// 64-k dot, column-pair, 4 batch streams. W[2j],W[2j+1] = weights of the two
// columns for k-index j. Sources may be LDS (h) or global (x); float4 reads.
__device__ __forceinline__ void dot64x2_4(
    const float* p0, const float* p1, const float* p2, const float* p3,
    const float (&W)[128],
    float& a00, float& a01, float& a10, float& a11,
    float& a20, float& a21, float& a30, float& a31) {
  a00 = a01 = a10 = a11 = a20 = a21 = a30 = a31 = 0.f;
#pragma unroll
  for (int j4 = 0; j4 < 16; ++j4) {
    float4 v0 = *(const float4*)(p0 + j4 * 4);
    float4 v1 = *(const float4*)(p1 + j4 * 4);
    float4 v2 = *(const float4*)(p2 + j4 * 4);
    float4 v3 = *(const float4*)(p3 + j4 * 4);
    const float* e0 = (const float*)&v0;
    const float* e1 = (const float*)&v1;
    const float* e2 = (const float*)&v2;
    const float* e3 = (const float*)&v3;
#pragma unroll
    for (int jj = 0; jj < 4; ++jj) {
      float w0 = W[2 * (4 * j4 + jj) + 0];
      float w1 = W[2 * (4 * j4 + jj) + 1];
      a00 += e0[jj] * w0; a01 += e0[jj] * w1;
      a10 += e1[jj] * w0; a11 += e1[jj] * w1;
      a20 += e2[jj] * w0; a21 += e2[jj] * w1;
      a30 += e3[jj] * w0; a31 += e3[jj] * w1;
    }
  }
}

__global__ __launch_bounds__(512, 2) void lstm_persistent(
    const float* __restrict__ x,
    const float* __restrict__ Wk,
    const float* __restrict__ Wr,
    const float* __restrict__ bias,
    float* __restrict__ out) {
  const int tid = (int)threadIdx.x;
  const int g   = (int)blockIdx.x & 7;
  const int w   = (int)blockIdx.x >> 3;
  const bool crit = (tid < 256);  // waves 0-3: recurrent/critical path
  const int idx = tid & 255;
  const int o   = idx >> 5;       // k-octant: k in [o*64, o*64+64)
  const int col0 = (idx & 31) * 2;                        // local column pair
  const int gcol = ((col0 >> 4) * UU) + w * 16 + (col0 & 15);  // col0, col0+1 adjacent

  // Per-thread weight slice: R (crit) or K (xz side). 64 k x 2 cols.
  {
  }
  const float* M = crit ? Wr : Wk;
  float W[128];
#pragma unroll
  for (int j = 0; j < 64; ++j) {
    float2 ww = *(const float2*)(M + (size_t)(o * 64 + j) * NCOL + gcol);
    W[2 * j] = ww.x; W[2 * j + 1] = ww.y;
  }

  __shared__ float LX[8][4][65];   // x-proj partials (octant, batch, col)
  __shared__ float LR[8][4][65];   // recurrent partials
  __shared__ float LXZ[2][4][66];  // reduced xz, parity by t
  __shared__ float LH[4][512];     // h(t-1) staged
  __shared__ float LB[64];         // bias slice

  if (tid < 64) LB[tid] = bias[(tid >> 4) * UU + w * 16 + (tid & 15)];

  // Global bases.
  const float* xb[4];
#pragma unroll
  for (int k = 0; k < 4; ++k)
    xb[k] = x + (size_t)(g * 4 + k) * TT * DD + o * 64;
  const unsigned* ou[4];
#pragma unroll
  for (int k = 0; k < 4; ++k)
    ou[k] = (const unsigned*)out + (size_t)(g * 4 + k) * TT * UU;

  // ---- prologue: xz(t=0) by waves 4-7 ----
  if (!crit) {
    float a00,a01,a10,a11,a20,a21,a30,a31;
    dot64x2_4(xb[0], xb[1], xb[2], xb[3], W,
              a00,a01,a10,a11,a20,a21,a30,a31);
    *(float2*)&LX[o][0][col0] = make_float2(a00, a01);
    *(float2*)&LX[o][1][col0] = make_float2(a10, a11);
    *(float2*)&LX[o][2][col0] = make_float2(a20, a21);
    *(float2*)&LX[o][3][col0] = make_float2(a30, a31);
  }
  __syncthreads();
  if (!crit) {
    int b2 = idx >> 6, c3 = idx & 63;
    float s = 0.f;
#pragma unroll
    for (int oo = 0; oo < 8; ++oo) s += LX[oo][b2][c3];
    LXZ[0][b2][c3] = s;
  }
  __syncthreads();

  const int b_own = tid >> 4;   // wave-0 update threads
  const int u_own = tid & 15;
  float c_state = 0.0f;

  for (int t = 0; t < TT; ++t) {
    // ---- phase 1 ----
    if (!crit) {
      if (t + 1 < TT) {  // x-projection for t+1
        float a00,a01,a10,a11,a20,a21,a30,a31;
        size_t off = (size_t)(t + 1) * DD;
        dot64x2_4(xb[0]+off, xb[1]+off, xb[2]+off, xb[3]+off, W,
                  a00,a01,a10,a11,a20,a21,a30,a31);
        *(float2*)&LX[o][0][col0] = make_float2(a00, a01);
        *(float2*)&LX[o][1][col0] = make_float2(a10, a11);
        *(float2*)&LX[o][2][col0] = make_float2(a20, a21);
        *(float2*)&LX[o][3][col0] = make_float2(a30, a31);
      }
    } else if (t > 0) {
      // Poll h(t-1) words directly (dataflow sync). 8 words/thread.
      size_t roff = (size_t)(t - 1) * UU;
      unsigned v0,v1,v2,v3,v4,v5,v6,v7;
      for (;;) {
        v0 = __hip_atomic_load(ou[0] + roff + idx,       __ATOMIC_RELAXED, __HIP_MEMORY_SCOPE_AGENT);
        v1 = __hip_atomic_load(ou[0] + roff + idx + 256, __ATOMIC_RELAXED, __HIP_MEMORY_SCOPE_AGENT);
        v2 = __hip_atomic_load(ou[1] + roff + idx,       __ATOMIC_RELAXED, __HIP_MEMORY_SCOPE_AGENT);
        v3 = __hip_atomic_load(ou[1] + roff + idx + 256, __ATOMIC_RELAXED, __HIP_MEMORY_SCOPE_AGENT);
        v4 = __hip_atomic_load(ou[2] + roff + idx,       __ATOMIC_RELAXED, __HIP_MEMORY_SCOPE_AGENT);
        v5 = __hip_atomic_load(ou[2] + roff + idx + 256, __ATOMIC_RELAXED, __HIP_MEMORY_SCOPE_AGENT);
        v6 = __hip_atomic_load(ou[3] + roff + idx,       __ATOMIC_RELAXED, __HIP_MEMORY_SCOPE_AGENT);
        v7 = __hip_atomic_load(ou[3] + roff + idx + 256, __ATOMIC_RELAXED, __HIP_MEMORY_SCOPE_AGENT);
        int ok = (v0 != SENT) & (v1 != SENT) & (v2 != SENT) & (v3 != SENT) &
                 (v4 != SENT) & (v5 != SENT) & (v6 != SENT) & (v7 != SENT);
        if (__all(ok)) break;
        __builtin_amdgcn_s_sleep(1);
      }
      LH[0][idx]       = __uint_as_float(v0);
      LH[0][idx + 256] = __uint_as_float(v1);
      LH[1][idx]       = __uint_as_float(v2);
      LH[1][idx + 256] = __uint_as_float(v3);
      LH[2][idx]       = __uint_as_float(v4);
      LH[2][idx + 256] = __uint_as_float(v5);
      LH[3][idx]       = __uint_as_float(v6);
      LH[3][idx + 256] = __uint_as_float(v7);
    }
    __syncthreads();
    // ---- phase 2 ----
    if (crit) {
      if (t > 0) {  // recurrent projection h(t-1) @ R
        float a00,a01,a10,a11,a20,a21,a30,a31;
        dot64x2_4(&LH[0][o * 64], &LH[1][o * 64], &LH[2][o * 64], &LH[3][o * 64],
                  W, a00,a01,a10,a11,a20,a21,a30,a31);
        *(float2*)&LR[o][0][col0] = make_float2(a00, a01);
        *(float2*)&LR[o][1][col0] = make_float2(a10, a11);
        *(float2*)&LR[o][2][col0] = make_float2(a20, a21);
        *(float2*)&LR[o][3][col0] = make_float2(a30, a31);
      }
    } else if (t + 1 < TT) {  // reduce xz(t+1) into parity slot
      int b2 = idx >> 6, c3 = idx & 63;
      float s = 0.f;
#pragma unroll
      for (int oo = 0; oo < 8; ++oo) s += LX[oo][b2][c3];
      LXZ[(t + 1) & 1][b2][c3] = s;
    }
    __syncthreads();
    // ---- phase 3: gates + state update + h store (wave 0) ----
    if (tid < 64) {
      float s0 = LXZ[t & 1][b_own][u_own +  0] + LB[u_own +  0];
      float s1 = LXZ[t & 1][b_own][u_own + 16] + LB[u_own + 16];
      float s2 = LXZ[t & 1][b_own][u_own + 32] + LB[u_own + 32];
      float s3 = LXZ[t & 1][b_own][u_own + 48] + LB[u_own + 48];
      if (t > 0) {
#pragma unroll
        for (int oo = 0; oo < 8; ++oo) {
          s0 += LR[oo][b_own][u_own +  0];
          s1 += LR[oo][b_own][u_own + 16];
          s2 += LR[oo][b_own][u_own + 32];
          s3 += LR[oo][b_own][u_own + 48];
        }
      }
      float gi = hsig(s0);
      float gf = hsig(s1);
      float gc = tanh_fast(s2);
      float go = hsig(s3);
      c_state = gf * c_state + gi * gc;
      float h = go * tanh_fast(c_state);
      __hip_atomic_store(
          out + ((size_t)(g * 4 + b_own) * TT + t) * UU + w * 16 + u_own, h,
          __ATOMIC_RELAXED, __HIP_MEMORY_SCOPE_AGENT);
    }
    // No barrier here: next iteration's pollers tolerate not-yet-written h.
  }
}

extern "C" void kernel_launch(void* const* d_in, const int* in_sizes, int n_in,
                              void* d_out, int out_size, void* d_ws, size_t ws_size,
                              hipStream_t stream) {
  const float* x    = (const float*)d_in[0];
  const float* Wk   = (const float*)d_in[1];
  const float* Wr   = (const float*)d_in[2];
  const float* bias = (const float*)d_in[3];
  float* out = (float*)d_out;

  // Sentinel-fill the h history (graph-capturable async memset).
  hipMemsetAsync(out, 0xFF, (size_t)out_size * sizeof(float), stream);
  lstm_persistent<<<256, 512, 0, stream>>>(x, Wk, Wr, bias, out);
}

// Round 5
// 4620.030 us; speedup vs baseline: 3.3479x; 1.4384x over previous
//
#include <hip/hip_runtime.h>

// LSTM forward, B=32 T=1024 D=512 U=512, fp32.
// Persistent fused kernel, 256 WGs x 512 thr (all co-resident, grid == #CUs).
// Group g = blockIdx&7 handles batches 4g..4g+3; WG w = blockIdx>>3 owns
// 16 units (64 gate columns). Weights in VGPRs: waves 0-3 hold R-slices
// (critical path), waves 4-7 hold K-slices (xz pipeline).
//
// R5: NO WG-wide barriers in the steady-state loop.
//  - xz waves free-run up to RDEPTH steps ahead: x@K -> partials -> reduce
//    into an LDS ring; throttled only by crit_done. Their compute + x-load
//    latency is fully off the critical path.
//  - crit waves: poll h(t-1) sentinels (R4-proven dataflow sync, LLC scope)
//    -> stage LDS -> h@R dot (s_setprio(1)) -> wave0 gates+store h(t).
//  - intra-WG sync: 4-wave epoch barriers via LDS atomics (ds_add + spin),
//    ~150cy, no global traffic, no cross-wave-group coupling.
// d_out doubles as h history; memset to 0xFFFFFFFF (sentinel) per launch.

#define TT 1024
#define DD 512
#define UU 512
#define NCOL 2048
#define SENT 0xFFFFFFFFu
#define RDEPTH 4

__device__ __forceinline__ float hsig(float v) {
  return fminf(fmaxf(0.2f * v + 0.5f, 0.0f), 1.0f);
}
__device__ __forceinline__ float tanh_fast(float x) {
  float e = __expf(2.0f * x);
  return 1.0f - 2.0f / (e + 1.0f);
}

// 64-k dot, column-pair, 4 batch streams. W[2j],W[2j+1] = weights of the two
// columns for k-index j. Sources may be LDS (h) or global (x); float4 reads.
__device__ __forceinline__ void dot64x2_4(
    const float* p0, const float* p1, const float* p2, const float* p3,
    const float (&W)[128],
    float& a00, float& a01, float& a10, float& a11,
    float& a20, float& a21, float& a30, float& a31) {
  a00 = a01 = a10 = a11 = a20 = a21 = a30 = a31 = 0.f;
#pragma unroll
  for (int j4 = 0; j4 < 16; ++j4) {
    float4 v0 = *(const float4*)(p0 + j4 * 4);
    float4 v1 = *(const float4*)(p1 + j4 * 4);
    float4 v2 = *(const float4*)(p2 + j4 * 4);
    float4 v3 = *(const float4*)(p3 + j4 * 4);
    const float* e0 = (const float*)&v0;
    const float* e1 = (const float*)&v1;
    const float* e2 = (const float*)&v2;
    const float* e3 = (const float*)&v3;
#pragma unroll
    for (int jj = 0; jj < 4; ++jj) {
      float w0 = W[2 * (4 * j4 + jj) + 0];
      float w1 = W[2 * (4 * j4 + jj) + 1];
      a00 += e0[jj] * w0; a01 += e0[jj] * w1;
      a10 += e1[jj] * w0; a11 += e1[jj] * w1;
      a20 += e2[jj] * w0; a21 += e2[jj] * w1;
      a30 += e3[jj] * w0; a31 += e3[jj] * w1;
    }
  }
}

// Epoch barrier for the 4 waves of one half (waves 0-3 or 4-7).
__device__ __forceinline__ void wavebar(int* ctr, int& ep) {
  asm volatile("s_waitcnt lgkmcnt(0)" ::: "memory");  // prior LDS writes done
  if ((threadIdx.x & 63) == 0)
    __hip_atomic_fetch_add(ctr, 1, __ATOMIC_RELAXED, __HIP_MEMORY_SCOPE_WORKGROUP);
  ep += 4;
  while (__hip_atomic_load(ctr, __ATOMIC_RELAXED, __HIP_MEMORY_SCOPE_WORKGROUP) < ep) {
  }
  asm volatile("" ::: "memory");
}

__global__ __launch_bounds__(512, 2) void lstm_persistent(
    const float* __restrict__ x,
    const float* __restrict__ Wk,
    const float* __restrict__ Wr,
    const float* __restrict__ bias,
    float* __restrict__ out) {
  const int tid = (int)threadIdx.x;
  const int g   = (int)blockIdx.x & 7;
  const int w   = (int)blockIdx.x >> 3;
  const bool crit = (tid < 256);
  const int idx = tid & 255;
  const int o   = idx >> 5;        // k-octant
  const int col0 = (idx & 31) * 2; // local column pair
  const int gcol = ((col0 >> 4) * UU) + w * 16 + (col0 & 15);

  const float* M = crit ? Wr : Wk;
  float W[128];
#pragma unroll
  for (int j = 0; j < 64; ++j) {
    float2 ww = *(const float2*)(M + (size_t)(o * 64 + j) * NCOL + gcol);
    W[2 * j] = ww.x; W[2 * j + 1] = ww.y;
  }

  __shared__ float LX[8][4][65];        // xz partials
  __shared__ float LR[8][4][65];        // recurrent partials
  __shared__ float RING[RDEPTH][4][66]; // reduced xz ring
  __shared__ float LH[4][512];          // h(t-1) staged
  __shared__ float LB[64];              // bias slice
  __shared__ int cXZdone, cCRITdone, cXZbar, cCRITbar;

  if (tid == 0) { cXZdone = 0; cCRITdone = 0; cXZbar = 0; cCRITbar = 0; }
  if (tid < 64) LB[tid] = bias[(tid >> 4) * UU + w * 16 + (tid & 15)];
  __syncthreads();  // one-time init barrier only

  if (crit) {
    // ---------------- critical pipeline: waves 0-3 ----------------
    const unsigned* ou0 = (const unsigned*)out + (size_t)(g * 4 + 0) * TT * UU;
    const unsigned* ou1 = (const unsigned*)out + (size_t)(g * 4 + 1) * TT * UU;
    const unsigned* ou2 = (const unsigned*)out + (size_t)(g * 4 + 2) * TT * UU;
    const unsigned* ou3 = (const unsigned*)out + (size_t)(g * 4 + 3) * TT * UU;
    const int b_own = tid >> 4;  // wave-0 update threads
    const int u_own = tid & 15;
    float c_state = 0.0f;
    int epC = 0;

    for (int t = 0; t < TT; ++t) {
      if (t > 0) {
        size_t roff = (size_t)(t - 1) * UU;
        unsigned v0, v1, v2, v3, v4, v5, v6, v7;
        for (;;) {
          v0 = __hip_atomic_load(ou0 + roff + idx,       __ATOMIC_RELAXED, __HIP_MEMORY_SCOPE_AGENT);
          v1 = __hip_atomic_load(ou0 + roff + idx + 256, __ATOMIC_RELAXED, __HIP_MEMORY_SCOPE_AGENT);
          v2 = __hip_atomic_load(ou1 + roff + idx,       __ATOMIC_RELAXED, __HIP_MEMORY_SCOPE_AGENT);
          v3 = __hip_atomic_load(ou1 + roff + idx + 256, __ATOMIC_RELAXED, __HIP_MEMORY_SCOPE_AGENT);
          v4 = __hip_atomic_load(ou2 + roff + idx,       __ATOMIC_RELAXED, __HIP_MEMORY_SCOPE_AGENT);
          v5 = __hip_atomic_load(ou2 + roff + idx + 256, __ATOMIC_RELAXED, __HIP_MEMORY_SCOPE_AGENT);
          v6 = __hip_atomic_load(ou3 + roff + idx,       __ATOMIC_RELAXED, __HIP_MEMORY_SCOPE_AGENT);
          v7 = __hip_atomic_load(ou3 + roff + idx + 256, __ATOMIC_RELAXED, __HIP_MEMORY_SCOPE_AGENT);
          int ok = (v0 != SENT) & (v1 != SENT) & (v2 != SENT) & (v3 != SENT) &
                   (v4 != SENT) & (v5 != SENT) & (v6 != SENT) & (v7 != SENT);
          if (__all(ok)) break;
          __builtin_amdgcn_s_sleep(1);
        }
        LH[0][idx]       = __uint_as_float(v0);
        LH[0][idx + 256] = __uint_as_float(v1);
        LH[1][idx]       = __uint_as_float(v2);
        LH[1][idx + 256] = __uint_as_float(v3);
        LH[2][idx]       = __uint_as_float(v4);
        LH[2][idx + 256] = __uint_as_float(v5);
        LH[3][idx]       = __uint_as_float(v6);
        LH[3][idx + 256] = __uint_as_float(v7);
      }
      wavebar(&cCRITbar, epC);  // B1: LH staged
      if (t > 0) {
        __builtin_amdgcn_s_setprio(1);
        float a00,a01,a10,a11,a20,a21,a30,a31;
        dot64x2_4(&LH[0][o * 64], &LH[1][o * 64], &LH[2][o * 64], &LH[3][o * 64],
                  W, a00,a01,a10,a11,a20,a21,a30,a31);
        *(float2*)&LR[o][0][col0] = make_float2(a00, a01);
        *(float2*)&LR[o][1][col0] = make_float2(a10, a11);
        *(float2*)&LR[o][2][col0] = make_float2(a20, a21);
        *(float2*)&LR[o][3][col0] = make_float2(a30, a31);
        __builtin_amdgcn_s_setprio(0);
      }
      wavebar(&cCRITbar, epC);  // B2: LR complete
      if (tid < 64) {
        // xz ring slot t must be produced (xz normally runs ahead -> no spin)
        while (__hip_atomic_load(&cXZdone, __ATOMIC_RELAXED,
                                 __HIP_MEMORY_SCOPE_WORKGROUP) < t + 1) {
        }
        asm volatile("" ::: "memory");
        const int s = t & (RDEPTH - 1);
        float s0 = RING[s][b_own][u_own +  0] + LB[u_own +  0];
        float s1 = RING[s][b_own][u_own + 16] + LB[u_own + 16];
        float s2 = RING[s][b_own][u_own + 32] + LB[u_own + 32];
        float s3 = RING[s][b_own][u_own + 48] + LB[u_own + 48];
        if (t > 0) {
#pragma unroll
          for (int oo = 0; oo < 8; ++oo) {
            s0 += LR[oo][b_own][u_own +  0];
            s1 += LR[oo][b_own][u_own + 16];
            s2 += LR[oo][b_own][u_own + 32];
            s3 += LR[oo][b_own][u_own + 48];
          }
        }
        float gi = hsig(s0);
        float gf = hsig(s1);
        float gc = tanh_fast(s2);
        float go = hsig(s3);
        c_state = gf * c_state + gi * gc;
        float h = go * tanh_fast(c_state);
        __hip_atomic_store(
            out + ((size_t)(g * 4 + b_own) * TT + t) * UU + w * 16 + u_own, h,
            __ATOMIC_RELAXED, __HIP_MEMORY_SCOPE_AGENT);
      }
      if (tid == 0) {
        asm volatile("s_waitcnt lgkmcnt(0)" ::: "memory");
        __hip_atomic_fetch_add(&cCRITdone, 1, __ATOMIC_RELAXED,
                               __HIP_MEMORY_SCOPE_WORKGROUP);
      }
    }
  } else {
    // ---------------- xz pipeline: waves 4-7 (free-running) ----------------
    const float* xb0 = x + (size_t)(g * 4 + 0) * TT * DD + o * 64;
    const float* xb1 = x + (size_t)(g * 4 + 1) * TT * DD + o * 64;
    const float* xb2 = x + (size_t)(g * 4 + 2) * TT * DD + o * 64;
    const float* xb3 = x + (size_t)(g * 4 + 3) * TT * DD + o * 64;
    int epX = 0;

    for (int t = 0; t < TT; ++t) {
      size_t off = (size_t)t * DD;
      float a00,a01,a10,a11,a20,a21,a30,a31;
      dot64x2_4(xb0 + off, xb1 + off, xb2 + off, xb3 + off, W,
                a00,a01,a10,a11,a20,a21,a30,a31);
      *(float2*)&LX[o][0][col0] = make_float2(a00, a01);
      *(float2*)&LX[o][1][col0] = make_float2(a10, a11);
      *(float2*)&LX[o][2][col0] = make_float2(a20, a21);
      *(float2*)&LX[o][3][col0] = make_float2(a30, a31);
      wavebar(&cXZbar, epX);  // partials visible
      // ring slot t&3 free? (consumed when cCRITdone >= t-RDEPTH+1)
      if (t >= RDEPTH) {
        while (__hip_atomic_load(&cCRITdone, __ATOMIC_RELAXED,
                                 __HIP_MEMORY_SCOPE_WORKGROUP) < t - RDEPTH + 1) {
          __builtin_amdgcn_s_sleep(1);
        }
        asm volatile("" ::: "memory");
      }
      {
        const int b2 = idx >> 6, c3 = idx & 63;
        float ssum = 0.f;
#pragma unroll
        for (int oo = 0; oo < 8; ++oo) ssum += LX[oo][b2][c3];
        RING[t & (RDEPTH - 1)][b2][c3] = ssum;
      }
      wavebar(&cXZbar, epX);  // reduce complete (also guards LX overwrite)
      if (idx == 0) {
        asm volatile("s_waitcnt lgkmcnt(0)" ::: "memory");
        __hip_atomic_fetch_add(&cXZdone, 1, __ATOMIC_RELAXED,
                               __HIP_MEMORY_SCOPE_WORKGROUP);
      }
    }
  }
}

extern "C" void kernel_launch(void* const* d_in, const int* in_sizes, int n_in,
                              void* d_out, int out_size, void* d_ws, size_t ws_size,
                              hipStream_t stream) {
  const float* x    = (const float*)d_in[0];
  const float* Wk   = (const float*)d_in[1];
  const float* Wr   = (const float*)d_in[2];
  const float* bias = (const float*)d_in[3];
  float* out = (float*)d_out;

  // Sentinel-fill the h history (graph-capturable async memset).
  hipMemsetAsync(out, 0xFF, (size_t)out_size * sizeof(float), stream);
  lstm_persistent<<<256, 512, 0, stream>>>(x, Wk, Wr, bias, out);
}